// Round 16
// baseline (1204.254 us; speedup 1.0000x reference)
//
#include <hip/hip_runtime.h>

typedef unsigned short u16;
typedef unsigned int u32;
typedef __bf16 bf16x8 __attribute__((ext_vector_type(8)));
typedef float f32x4 __attribute__((ext_vector_type(4)));
typedef float f32x16 __attribute__((ext_vector_type(16)));

__device__ __forceinline__ u16 f2bf(float f) {
    union { float f; u32 u; } v; v.f = f;
    u32 r = v.u + 0x7FFFu + ((v.u >> 16) & 1u);
    return (u16)(r >> 16);
}

__device__ __forceinline__ u16 bfu(float x) {
    __bf16 b = (__bf16)x;
    union { __bf16 b; u16 u; } c; c.b = b; return c.u;
}

// v_permlane32_swap_b32 (R13-verified): swaps vdst[32:63] <-> vsrc[0:31].
__device__ __forceinline__ void pl32swap(u32& a, u32& b) {
    asm volatile("v_permlane32_swap_b32 %0, %1" : "+v"(a), "+v"(b));
}

__device__ __forceinline__ void gload16(const u16* g, u16* l) {
    __builtin_amdgcn_global_load_lds((const __attribute__((address_space(1))) void*)g,
                                     (__attribute__((address_space(3))) void*)l, 16, 0, 0);
}

// ---------------- weight transpose + bf16 convert: Wt[n][k] = bf16(W[k][n]) ----------------
__global__ void wtrans(const float* __restrict__ W, u16* __restrict__ Wt,
                       int K, int N, int rowOff, int dstLd, long long dstStride)
{
    __shared__ float tile[32][33];
    const int l = blockIdx.z;
    const float* Wl = W + (size_t)l * K * N;
    u16* Wtl = Wt + (size_t)l * dstStride;
    const int tx = threadIdx.x, ty = threadIdx.y;
    const int x = blockIdx.x * 32 + tx;
    const int y0 = blockIdx.y * 32;
#pragma unroll
    for (int j = 0; j < 32; j += 8) tile[ty + j][tx] = Wl[(size_t)(y0 + ty + j) * N + x];
    __syncthreads();
    const int n0 = blockIdx.x * 32;
    const int k = y0 + tx;
#pragma unroll
    for (int j = 0; j < 32; j += 8)
        Wtl[(size_t)(rowOff + n0 + ty + j) * dstLd + k] = f2bf(tile[tx][ty + j]);
}

// ---------------- input projection: x = src @ W_in + b_in  (K=3) ----------------
__global__ __launch_bounds__(256) void input_proj(const float* __restrict__ src,
    const float* __restrict__ Wi, const float* __restrict__ bi,
    float* __restrict__ xf, u16* __restrict__ xb)
{
    int idx = blockIdx.x * 256 + threadIdx.x;   // over 8192*512
    int m = idx >> 9, n = idx & 511;
    float v = bi[n] + src[m * 3] * Wi[n] + src[m * 3 + 1] * Wi[512 + n] + src[m * 3 + 2] * Wi[1024 + n];
    xf[idx] = v;
    xb[idx] = f2bf(v);
}

// ---------------- GEMM 256x256, BK=32, 4-slot counted-vmcnt pipeline (T3+T4) ----------------
// K MUST be 512 (16 K-tiles). 512 threads = 8 waves (2M x 4N), per-wave out 128x64.
// LDS: 4 slots x (A 16KB + B 16KB) = 128KB. Tile rows packed 2-per-128B super-row,
// granule ^= (R&7) -> 8-way bank spread. Stage: 4 loads/thread/tile; at iter t,
// vmcnt(8) leaves tiles t+1,t+2 in flight -> tile t landed. Raw s_barrier (no drain).
// EPI 1: Cb = bf16(relu(acc+bias)).  EPI 2: QKV split writes (Q pre-scaled 0.125*log2e).
__device__ __forceinline__ void stage_tile256(const u16* __restrict__ G, int ld, int row0,
                                              int k0, u16* lds, int tid)
{
#pragma unroll
    for (int j = 0; j < 2; j++) {
        int s = tid + j * 512;
        int R = s >> 3;
        int u = (s & 7) ^ (R & 7);
        int r = 2 * R + (u >> 2);
        int gc = u & 3;
        gload16(G + (size_t)(row0 + r) * ld + k0 + gc * 8, lds + s * 8);
    }
}

template<int EPI>
__global__ __launch_bounds__(512, 2) void gemm256(
    const u16* __restrict__ A, const u16* __restrict__ Bt,
    const float* __restrict__ bias, u16* __restrict__ Cb,
    u16* __restrict__ Qo, u16* __restrict__ Ko, u16* __restrict__ Vo,
    const float* __restrict__ bq, const float* __restrict__ bk, const float* __restrict__ bv,
    int M, int N, int K)
{
    __shared__ u16 As[4][8192];   // [slot][128 super-rows][64 u16]
    __shared__ u16 Bs[4][8192];
    const int tid = threadIdx.x, lane = tid & 63, wid = tid >> 6;
    const int wm = wid >> 2, wn = wid & 3;
    const int row0 = blockIdx.y * 256, col0 = blockIdx.x * 256;
    const int cc = lane & 15, qg = lane >> 4;
    f32x4 acc[8][4] = {};

    // prologue: stage tiles 0,1,2 into slots 0,1,2
    stage_tile256(A, K, row0, 0, As[0], tid);  stage_tile256(Bt, K, col0, 0, Bs[0], tid);
    stage_tile256(A, K, row0, 32, As[1], tid); stage_tile256(Bt, K, col0, 32, Bs[1], tid);
    stage_tile256(A, K, row0, 64, As[2], tid); stage_tile256(Bt, K, col0, 64, Bs[2], tid);

    for (int t = 0; t < 16; ++t) {
        // counted wait: own loads of tile t landed (tiles t+1,t+2 may stay in flight)
        if (t <= 13)      asm volatile("s_waitcnt vmcnt(8)" ::: "memory");
        else if (t == 14) asm volatile("s_waitcnt vmcnt(4)" ::: "memory");
        else              asm volatile("s_waitcnt vmcnt(0)" ::: "memory");
        __builtin_amdgcn_s_barrier();          // raw barrier: no compiler drain
        __builtin_amdgcn_sched_barrier(0);
        if (t + 3 < 16) {                      // prefetch tile t+3 into slot (t+3)&3
            int sl = (t + 3) & 3, k0 = (t + 3) * 32;
            stage_tile256(A, K, row0, k0, As[sl], tid);
            stage_tile256(Bt, K, col0, k0, Bs[sl], tid);
        }
        const int cs = t & 3;
        bf16x8 af[8], bfr[4];
#pragma unroll
        for (int i = 0; i < 8; i++) {
            int r = wm * 128 + i * 16 + cc;
            int R = r >> 1;
            int g = (((r & 1) << 2) | qg) ^ (R & 7);
            af[i] = *(const bf16x8*)&As[cs][R * 64 + g * 8];
        }
#pragma unroll
        for (int i = 0; i < 4; i++) {
            int r = wn * 64 + i * 16 + cc;
            int R = r >> 1;
            int g = (((r & 1) << 2) | qg) ^ (R & 7);
            bfr[i] = *(const bf16x8*)&Bs[cs][R * 64 + g * 8];
        }
        asm volatile("s_waitcnt lgkmcnt(0)" ::: "memory");
        __builtin_amdgcn_sched_barrier(0);
        __builtin_amdgcn_s_setprio(1);
#pragma unroll
        for (int mi = 0; mi < 8; mi++)
#pragma unroll
            for (int ni = 0; ni < 4; ni++)
                acc[mi][ni] = __builtin_amdgcn_mfma_f32_16x16x32_bf16(af[mi], bfr[ni], acc[mi][ni], 0, 0, 0);
        __builtin_amdgcn_s_setprio(0);
    }
    // epilogue: D layout col = lane&15, row = (lane>>4)*4 + i
    const int q4 = qg * 4;
    if (EPI == 2) {
#pragma unroll
        for (int mi = 0; mi < 8; mi++) {
            int grow = row0 + wm * 128 + mi * 16 + q4;
            int btok = grow >> 11, srem = grow & 2047;
#pragma unroll
            for (int ni = 0; ni < 4; ni++) {
                int gcol = col0 + wn * 64 + ni * 16 + cc;
                int sec = gcol >> 9, f = gcol & 511;
                int hh = f >> 6, dd = f & 63;
                if (sec == 0) {
                    float bb = bq[f];
                    size_t base = (((size_t)btok * 8 + hh) * 2048 + srem) * 64 + dd;
#pragma unroll
                    for (int i = 0; i < 4; i++) Qo[base + (size_t)i * 64] = f2bf((acc[mi][ni][i] + bb) * 0.18033688f);
                } else if (sec == 1) {
                    float bb = bk[f];
                    size_t base = (((size_t)btok * 8 + hh) * 2048 + srem) * 64 + dd;
#pragma unroll
                    for (int i = 0; i < 4; i++) Ko[base + (size_t)i * 64] = f2bf(acc[mi][ni][i] + bb);
                } else {
                    float bb = bv[f];
                    size_t base = (((size_t)btok * 8 + hh) * 64 + dd) * 2048 + srem;
#pragma unroll
                    for (int i = 0; i < 4; i++) Vo[base + i] = f2bf(acc[mi][ni][i] + bb);
                }
            }
        }
    } else {
#pragma unroll
        for (int mi = 0; mi < 8; mi++) {
            int grow = row0 + wm * 128 + mi * 16 + q4;
#pragma unroll
            for (int ni = 0; ni < 4; ni++) {
                int gcol = col0 + wn * 64 + ni * 16 + cc;
                float bb = bias[gcol];
#pragma unroll
                for (int i = 0; i < 4; i++) {
                    float v = acc[mi][ni][i] + bb;
                    Cb[(size_t)(grow + i) * N + gcol] = f2bf(v > 0.f ? v : 0.f);
                }
            }
        }
    }
}

// ---------------- GEMM 64x64 tile, BK=64, double-buffered, fused residual add ----------------
// Cf = A @ Bt^T + bias + Rf.  grid (N/64, M/64) = 1024 blocks = 4/CU. 4 waves of 32x32.
__global__ __launch_bounds__(256) void gemm64_db(
    const u16* __restrict__ A, const u16* __restrict__ Bt,
    const float* __restrict__ bias, const float* __restrict__ Rf,
    float* __restrict__ Cf, int M, int N, int K)
{
    __shared__ u16 As[2][64 * 64];   // 8KB each, granule ^= row&7
    __shared__ u16 Bs[2][64 * 64];
    const int tid = threadIdx.x;
    const int lane = tid & 63, wid = tid >> 6;
    const int row0 = blockIdx.y * 64, col0 = blockIdx.x * 64;
    const int wr = (wid >> 1) * 32, wc = (wid & 1) * 32;
    const int cc = lane & 15, qg = lane >> 4;
    const int r0 = tid >> 3, g8 = (tid & 7);
    const int gsw0 = (g8 ^ (r0 & 7)) * 8;
    const int r1 = r0 + 32;
    const int gsw1 = (g8 ^ (r1 & 7)) * 8;
    f32x4 acc[2][2] = {};
    gload16(A + (size_t)(row0 + r0) * K + gsw0, &As[0][tid * 8]);
    gload16(A + (size_t)(row0 + r1) * K + gsw1, &As[0][(tid + 256) * 8]);
    gload16(Bt + (size_t)(col0 + r0) * K + gsw0, &Bs[0][tid * 8]);
    gload16(Bt + (size_t)(col0 + r1) * K + gsw1, &Bs[0][(tid + 256) * 8]);
    int cur = 0;
    for (int k0 = 0; k0 < K; k0 += 64) {
        asm volatile("s_waitcnt vmcnt(0)" ::: "memory");
        __syncthreads();
        if (k0 + 64 < K) {
            int kn = k0 + 64, nb = cur ^ 1;
            gload16(A + (size_t)(row0 + r0) * K + kn + gsw0, &As[nb][tid * 8]);
            gload16(A + (size_t)(row0 + r1) * K + kn + gsw1, &As[nb][(tid + 256) * 8]);
            gload16(Bt + (size_t)(col0 + r0) * K + kn + gsw0, &Bs[nb][tid * 8]);
            gload16(Bt + (size_t)(col0 + r1) * K + kn + gsw1, &Bs[nb][(tid + 256) * 8]);
        }
        bf16x8 af[2][2], bfr[2][2];
#pragma unroll
        for (int i = 0; i < 2; i++) {
            int r = wr + i * 16 + cc;
#pragma unroll
            for (int kk = 0; kk < 2; kk++)
                af[i][kk] = *(const bf16x8*)&As[cur][r * 64 + ((kk * 4 + qg) ^ (r & 7)) * 8];
        }
#pragma unroll
        for (int i = 0; i < 2; i++) {
            int r = wc + i * 16 + cc;
#pragma unroll
            for (int kk = 0; kk < 2; kk++)
                bfr[i][kk] = *(const bf16x8*)&Bs[cur][r * 64 + ((kk * 4 + qg) ^ (r & 7)) * 8];
        }
        __builtin_amdgcn_s_setprio(1);
#pragma unroll
        for (int mi = 0; mi < 2; mi++)
#pragma unroll
            for (int ni = 0; ni < 2; ni++) {
                acc[mi][ni] = __builtin_amdgcn_mfma_f32_16x16x32_bf16(af[mi][0], bfr[ni][0], acc[mi][ni], 0, 0, 0);
                acc[mi][ni] = __builtin_amdgcn_mfma_f32_16x16x32_bf16(af[mi][1], bfr[ni][1], acc[mi][ni], 0, 0, 0);
            }
        __builtin_amdgcn_s_setprio(0);
        cur ^= 1;
    }
    const int q4 = qg * 4;
#pragma unroll
    for (int mi = 0; mi < 2; mi++) {
        int grow = row0 + wr + mi * 16 + q4;
#pragma unroll
        for (int ni = 0; ni < 2; ni++) {
            int gcol = col0 + wc + ni * 16 + cc;
            float bb = bias[gcol];
#pragma unroll
            for (int i = 0; i < 4; i++) {
                size_t idx = (size_t)(grow + i) * N + gcol;
                Cf[idx] = acc[mi][ni][i] + bb + Rf[idx];
            }
        }
    }
}

// ---------------- flash attention v8: fixed-max softmax + permlane P-exchange ----------------
__global__ __launch_bounds__(256) void flash_attn(
    const u16* __restrict__ Qb, const u16* __restrict__ Kb, const u16* __restrict__ Vt,
    u16* __restrict__ Ob)
{
    __shared__ u16 Ks[2][4096];
    __shared__ u16 Vs[2][4096];
    const int tid = threadIdx.x, lane = tid & 63, w = tid >> 6;
    const int l31 = lane & 31, h = lane >> 5;
    const int bh = blockIdx.x, qt = blockIdx.y;
    const u16* Kg = Kb + (size_t)bh * (2048 * 64);
    const u16* Vg = Vt + (size_t)bh * (64 * 2048);

    bf16x8 qf[4];
    {
        const u16* Qrow = Qb + ((size_t)bh * 2048 + (size_t)qt * 128 + w * 32 + l31) * 64;
#pragma unroll
        for (int f = 0; f < 4; f++) qf[f] = *(const bf16x8*)(Qrow + f * 16 + h * 8);
    }
    f32x16 os0{}, os1{};
    float lsum = 0.f;

    const int r8 = lane >> 3;
    const int cswz = ((lane & 7) ^ r8) * 8;
#pragma unroll
    for (int cc = 0; cc < 2; cc++) {
        int c = w * 2 + cc;
        gload16(Kg + (size_t)(c * 8 + r8) * 64 + cswz, &Ks[0][c * 512]);
        gload16(Vg + (size_t)(c * 8 + r8) * 2048 + cswz, &Vs[0][c * 512]);
    }
    const int swz = (l31 & 7) << 3;

    for (int kt = 0; kt < 32; kt++) {
        const int cur = kt & 1;
        asm volatile("s_waitcnt vmcnt(0)" ::: "memory");
        __syncthreads();
        if (kt < 31) {
#pragma unroll
            for (int cc = 0; cc < 2; cc++) {
                int c = w * 2 + cc;
                gload16(Kg + (size_t)(kt + 1) * 4096 + (size_t)(c * 8 + r8) * 64 + cswz, &Ks[cur ^ 1][c * 512]);
                gload16(Vg + (size_t)(c * 8 + r8) * 2048 + (size_t)(kt + 1) * 64 + cswz, &Vs[cur ^ 1][c * 512]);
            }
        }
        f32x16 p0{}, p1{};
        {
            const u16* kb = &Ks[cur][0];
            __builtin_amdgcn_s_setprio(1);
#pragma unroll
            for (int f = 0; f < 4; f++) {
                int colu = (f * 16 + h * 8) ^ swz;
                bf16x8 ka0 = *(const bf16x8*)(kb + l31 * 64 + colu);
                bf16x8 ka1 = *(const bf16x8*)(kb + (32 + l31) * 64 + colu);
                p0 = __builtin_amdgcn_mfma_f32_32x32x16_bf16(ka0, qf[f], p0, 0, 0, 0);
                p1 = __builtin_amdgcn_mfma_f32_32x32x16_bf16(ka1, qf[f], p1, 0, 0, 0);
            }
            __builtin_amdgcn_s_setprio(0);
        }
        float ss[4] = {};
#pragma unroll
        for (int r = 0; r < 16; r++) { float e = __builtin_amdgcn_exp2f(p0[r]); p0[r] = e; ss[r & 3] += e; }
#pragma unroll
        for (int r = 0; r < 16; r++) { float e = __builtin_amdgcn_exp2f(p1[r]); p1[r] = e; ss[r & 3] += e; }
        lsum += (ss[0] + ss[1]) + (ss[2] + ss[3]);
        const u16* vb = &Vs[cur][0];
#pragma unroll
        for (int t = 0; t < 2; t++) {
            u32 pk[8];
#pragma unroll
            for (int j = 0; j < 8; j++) {
                float a = t ? p1[2 * j] : p0[2 * j];
                float b = t ? p1[2 * j + 1] : p0[2 * j + 1];
                pk[j] = (u32)bfu(a) | ((u32)bfu(b) << 16);
            }
            u32 x0 = pk[0], y0 = pk[2]; pl32swap(x0, y0);
            u32 x1 = pk[1], y1 = pk[3]; pl32swap(x1, y1);
            u32 x2 = pk[4], y2 = pk[6]; pl32swap(x2, y2);
            u32 x3 = pk[5], y3 = pk[7]; pl32swap(x3, y3);
            union { u32 u[4]; bf16x8 v; } fA, fB;
            fA.u[0] = x0; fA.u[1] = x1; fA.u[2] = y0; fA.u[3] = y1;
            fB.u[0] = x2; fB.u[1] = x3; fB.u[2] = y2; fB.u[3] = y3;
            __builtin_amdgcn_s_setprio(1);
#pragma unroll
            for (int f = 0; f < 2; f++) {
                bf16x8 pa = f ? fB.v : fA.v;
                int colu = (t * 32 + f * 16 + h * 8) ^ swz;
                bf16x8 v0 = *(const bf16x8*)(vb + l31 * 64 + colu);
                bf16x8 v1 = *(const bf16x8*)(vb + (32 + l31) * 64 + colu);
                os0 = __builtin_amdgcn_mfma_f32_32x32x16_bf16(pa, v0, os0, 0, 0, 0);
                os1 = __builtin_amdgcn_mfma_f32_32x32x16_bf16(pa, v1, os1, 0, 0, 0);
            }
            __builtin_amdgcn_s_setprio(0);
        }
    }
    lsum += __shfl_xor(lsum, 32);
    float rl = 1.f / lsum;
    const int hatt = bh & 7, b_ = bh >> 3;
#pragma unroll
    for (int r = 0; r < 16; r++) {
        int qrow = (r & 3) + 8 * (r >> 2) + 4 * h;
        float rlq = __shfl(rl, qrow);
        int tok = qt * 128 + w * 32 + qrow;
        u16* po = Ob + ((size_t)b_ * 2048 + tok) * 512 + hatt * 64;
        po[l31] = bfu(os0[r] * rlq);
        po[32 + l31] = bfu(os1[r] * rlq);
    }
}

// ---------------- single-input LayerNorm (residual pre-added in GEMM epilogue) --------------
__global__ __launch_bounds__(256) void ln_one(
    const float* __restrict__ Y,
    const float* __restrict__ g, const float* __restrict__ bta,
    float* __restrict__ Of, u16* __restrict__ Ob)
{
    const int lane = threadIdx.x & 63;
    const int row = blockIdx.x * 4 + (threadIdx.x >> 6);
    const size_t base = (size_t)row * 512 + lane * 8;
    float4 y0 = *(const float4*)(Y + base);
    float4 y1 = *(const float4*)(Y + base + 4);
    float t[8] = {y0.x, y0.y, y0.z, y0.w, y1.x, y1.y, y1.z, y1.w};
    float s = 0.f, s2 = 0.f;
#pragma unroll
    for (int j = 0; j < 8; j++) { s += t[j]; s2 += t[j] * t[j]; }
#pragma unroll
    for (int off = 1; off < 64; off <<= 1) { s += __shfl_xor(s, off); s2 += __shfl_xor(s2, off); }
    float mean = s * (1.f / 512.f);
    float var = s2 * (1.f / 512.f) - mean * mean;
    float rs = rsqrtf(var + 1e-5f);
    float4 g0 = *(const float4*)(g + lane * 8);
    float4 g1 = *(const float4*)(g + lane * 8 + 4);
    float4 b0 = *(const float4*)(bta + lane * 8);
    float4 b1 = *(const float4*)(bta + lane * 8 + 4);
    float gg[8] = {g0.x, g0.y, g0.z, g0.w, g1.x, g1.y, g1.z, g1.w};
    float bb[8] = {b0.x, b0.y, b0.z, b0.w, b1.x, b1.y, b1.z, b1.w};
    float o[8];
#pragma unroll
    for (int j = 0; j < 8; j++) o[j] = (t[j] - mean) * rs * gg[j] + bb[j];
    *(float4*)(Of + base) = make_float4(o[0], o[1], o[2], o[3]);
    *(float4*)(Of + base + 4) = make_float4(o[4], o[5], o[6], o[7]);
    u32 p0 = (u32)f2bf(o[0]) | ((u32)f2bf(o[1]) << 16);
    u32 p1 = (u32)f2bf(o[2]) | ((u32)f2bf(o[3]) << 16);
    u32 p2 = (u32)f2bf(o[4]) | ((u32)f2bf(o[5]) << 16);
    u32 p3 = (u32)f2bf(o[6]) | ((u32)f2bf(o[7]) << 16);
    *(uint4*)(Ob + base) = make_uint4(p0, p1, p2, p3);
}

// ---------------- output projection: out = x @ W_out + b_out (N=20, fp32), ILP 4 ----------------
__global__ __launch_bounds__(320) void out_proj(const float* __restrict__ x,
    const float* __restrict__ W, const float* __restrict__ b, float* __restrict__ out)
{
    int t = blockIdx.x * 320 + threadIdx.x;
    int m = t / 20, o = t - m * 20;
    const float* xr = x + (size_t)m * 512;
    float a0 = b[o], a1 = 0.f, a2 = 0.f, a3 = 0.f;
#pragma unroll 4
    for (int k = 0; k < 512; k += 4) {
        a0 = fmaf(xr[k],     W[k * 20 + o],       a0);
        a1 = fmaf(xr[k + 1], W[(k + 1) * 20 + o], a1);
        a2 = fmaf(xr[k + 2], W[(k + 2) * 20 + o], a2);
        a3 = fmaf(xr[k + 3], W[(k + 3) * 20 + o], a3);
    }
    out[(size_t)m * 20 + o] = (a0 + a1) + (a2 + a3);
}

extern "C" void kernel_launch(void* const* d_in, const int* in_sizes, int n_in,
                              void* d_out, int out_size, void* d_ws, size_t ws_size,
                              hipStream_t stream)
{
    const float* src  = (const float*)d_in[0];
    const float* W_in = (const float*)d_in[1];
    const float* b_in = (const float*)d_in[2];
    const float* Wq   = (const float*)d_in[3];
    const float* bq   = (const float*)d_in[4];
    const float* Wk   = (const float*)d_in[5];
    const float* bk   = (const float*)d_in[6];
    const float* Wv   = (const float*)d_in[7];
    const float* bv   = (const float*)d_in[8];
    const float* Wo   = (const float*)d_in[9];
    const float* bo   = (const float*)d_in[10];
    const float* ln1g = (const float*)d_in[11];
    const float* ln1b = (const float*)d_in[12];
    const float* W1   = (const float*)d_in[13];
    const float* b1   = (const float*)d_in[14];
    const float* W2   = (const float*)d_in[15];
    const float* b2   = (const float*)d_in[16];
    const float* ln2g = (const float*)d_in[17];
    const float* ln2b = (const float*)d_in[18];
    const float* Wout = (const float*)d_in[19];
    const float* bout = (const float*)d_in[20];

    char* ws = (char*)d_ws;
    size_t off = 0;
    auto take = [&](size_t bytes) -> void* {
        off = (off + 255) & ~(size_t)255;
        void* p = ws + off;
        off += bytes;
        return p;
    };
    const size_t TOK = 8192, D = 512;
    u16*   qkvt = (u16*)take(6ull * 1536 * 512 * 2);
    u16*   wot  = (u16*)take(6ull * 512 * 512 * 2);
    u16*   w1t  = (u16*)take(6ull * 2048 * 512 * 2);
    u16*   w2t  = (u16*)take(6ull * 512 * 2048 * 2);
    float* xf   = (float*)take(TOK * D * 4);
    u16*   xb   = (u16*)take(TOK * D * 2);
    u16*   sh4  = (u16*)take(4ull * TOK * D * 2);   // qb|kb|vtb|ob, reused as ff
    float* scr  = (float*)take(TOK * D * 4);
    float* h1f  = (float*)take(TOK * D * 4);
    u16*   h1b  = (u16*)take(TOK * D * 2);
    if (off > ws_size) return;

    u16* qb  = sh4;
    u16* kb_ = sh4 + TOK * D;
    u16* vtb = sh4 + 2 * TOK * D;
    u16* ob  = sh4 + 3 * TOK * D;
    u16* ffb = sh4;              // [8192][2048] bf16, alias of q/k/v/o region

    dim3 tb(32, 8);
    wtrans<<<dim3(16, 16, 6), tb, 0, stream>>>(Wq, qkvt, 512, 512, 0,    512, 1536ll * 512);
    wtrans<<<dim3(16, 16, 6), tb, 0, stream>>>(Wk, qkvt, 512, 512, 512,  512, 1536ll * 512);
    wtrans<<<dim3(16, 16, 6), tb, 0, stream>>>(Wv, qkvt, 512, 512, 1024, 512, 1536ll * 512);
    wtrans<<<dim3(16, 16, 6), tb, 0, stream>>>(Wo, wot,  512, 512, 0,    512, 512ll * 512);
    wtrans<<<dim3(64, 16, 6), tb, 0, stream>>>(W1, w1t,  512, 2048, 0,   512, 2048ll * 512);
    wtrans<<<dim3(16, 64, 6), tb, 0, stream>>>(W2, w2t,  2048, 512, 0,  2048, 512ll * 2048);

    input_proj<<<16384, 256, 0, stream>>>(src, W_in, b_in, xf, xb);

    for (int l = 0; l < 6; l++) {
        const u16* qkvt_l = qkvt + (size_t)l * 1536 * 512;
        const u16* wot_l  = wot  + (size_t)l * 512 * 512;
        const u16* w1t_l  = w1t  + (size_t)l * 2048 * 512;
        const u16* w2t_l  = w2t  + (size_t)l * 512 * 2048;

        gemm256<2><<<dim3(6, 32), 512, 0, stream>>>(xb, qkvt_l, nullptr,
            nullptr, qb, kb_, vtb,
            bq + l * 512, bk + l * 512, bv + l * 512, 8192, 1536, 512);

        flash_attn<<<dim3(32, 16), 256, 0, stream>>>(qb, kb_, vtb, ob);

        // scr = attn @ Wo + bo + x   (residual fused into epilogue)
        gemm64_db<<<dim3(8, 128), 256, 0, stream>>>(ob, wot_l, bo + l * 512,
            xf, scr, 8192, 512, 512);

        ln_one<<<2048, 256, 0, stream>>>(scr, ln1g + l * 512, ln1b + l * 512, h1f, h1b);

        gemm256<1><<<dim3(8, 32), 512, 0, stream>>>(h1b, w1t_l, b1 + l * 2048,
            ffb, nullptr, nullptr, nullptr, nullptr, nullptr, nullptr, 8192, 2048, 512);

        // scr = ff @ W2 + b2 + h   (residual fused into epilogue)
        gemm64_db<<<dim3(8, 128), 256, 0, stream>>>(ffb, w2t_l, b2 + l * 512,
            h1f, scr, 8192, 512, 2048);

        ln_one<<<2048, 256, 0, stream>>>(scr, ln2g + l * 512, ln2b + l * 512, xf, xb);
    }

    out_proj<<<512, 320, 0, stream>>>(xf, Wout, bout, (float*)d_out);
}

// Round 17
// 1100.173 us; speedup vs baseline: 1.0946x; 1.0946x over previous
//
#include <hip/hip_runtime.h>

typedef unsigned short u16;
typedef unsigned int u32;
typedef __bf16 bf16x8 __attribute__((ext_vector_type(8)));
typedef float f32x4 __attribute__((ext_vector_type(4)));
typedef float f32x16 __attribute__((ext_vector_type(16)));

__device__ __forceinline__ u16 f2bf(float f) {
    union { float f; u32 u; } v; v.f = f;
    u32 r = v.u + 0x7FFFu + ((v.u >> 16) & 1u);
    return (u16)(r >> 16);
}

__device__ __forceinline__ u16 bfu(float x) {
    __bf16 b = (__bf16)x;
    union { __bf16 b; u16 u; } c; c.b = b; return c.u;
}

// v_permlane32_swap_b32 (R13-verified): swaps vdst[32:63] <-> vsrc[0:31].
__device__ __forceinline__ void pl32swap(u32& a, u32& b) {
    asm volatile("v_permlane32_swap_b32 %0, %1" : "+v"(a), "+v"(b));
}

__device__ __forceinline__ void gload16(const u16* g, u16* l) {
    __builtin_amdgcn_global_load_lds((const __attribute__((address_space(1))) void*)g,
                                     (__attribute__((address_space(3))) void*)l, 16, 0, 0);
}

// ---------------- weight transpose + bf16 convert: Wt[n][k] = bf16(W[k][n]) ----------------
__global__ void wtrans(const float* __restrict__ W, u16* __restrict__ Wt,
                       int K, int N, int rowOff, int dstLd, long long dstStride)
{
    __shared__ float tile[32][33];
    const int l = blockIdx.z;
    const float* Wl = W + (size_t)l * K * N;
    u16* Wtl = Wt + (size_t)l * dstStride;
    const int tx = threadIdx.x, ty = threadIdx.y;
    const int x = blockIdx.x * 32 + tx;
    const int y0 = blockIdx.y * 32;
#pragma unroll
    for (int j = 0; j < 32; j += 8) tile[ty + j][tx] = Wl[(size_t)(y0 + ty + j) * N + x];
    __syncthreads();
    const int n0 = blockIdx.x * 32;
    const int k = y0 + tx;
#pragma unroll
    for (int j = 0; j < 32; j += 8)
        Wtl[(size_t)(rowOff + n0 + ty + j) * dstLd + k] = f2bf(tile[tx][ty + j]);
}

// ---------------- input projection: x = src @ W_in + b_in  (K=3) ----------------
__global__ __launch_bounds__(256) void input_proj(const float* __restrict__ src,
    const float* __restrict__ Wi, const float* __restrict__ bi,
    float* __restrict__ xf, u16* __restrict__ xb)
{
    int idx = blockIdx.x * 256 + threadIdx.x;   // over 8192*512
    int m = idx >> 9, n = idx & 511;
    float v = bi[n] + src[m * 3] * Wi[n] + src[m * 3 + 1] * Wi[512 + n] + src[m * 3 + 2] * Wi[1024 + n];
    xf[idx] = v;
    xb[idx] = f2bf(v);
}

// ---------------- bf16 GEMM 128x128, BK=64, T2-swizzled LDS ----------------
// EPI 1: Cb = bf16(relu(acc+bias)).  EPI 2: QKV split writes (Q pre-scaled by 0.125*log2e).
template<int EPI>
__global__ __launch_bounds__(256) void gemm_bt(
    const u16* __restrict__ A, const u16* __restrict__ Bt,
    const float* __restrict__ bias,
    float* __restrict__ Cf, u16* __restrict__ Cb,
    u16* __restrict__ Qo, u16* __restrict__ Ko, u16* __restrict__ Vo,
    const float* __restrict__ bq, const float* __restrict__ bk, const float* __restrict__ bv,
    int M, int N, int K)
{
    __shared__ u16 As[128 * 64];   // 16KB, granule ^= row&7
    __shared__ u16 Bs[128 * 64];   // 16KB
    const int tid = threadIdx.x;
    const int lane = tid & 63, wid = tid >> 6;
    const int row0 = blockIdx.y * 128, col0 = blockIdx.x * 128;
    const int wr = (wid >> 1) * 64, wc = (wid & 1) * 64;
    const int cc = lane & 15, qg = lane >> 4;
    const int sr = tid >> 3, sg = tid & 7;    // staging row (0..31 per j), granule
    f32x4 acc[4][4] = {};
    for (int k0 = 0; k0 < K; k0 += 64) {
        __syncthreads();                       // previous iter's LDS reads done
#pragma unroll
        for (int j = 0; j < 4; j++) {
            int r = j * 32 + sr;
            int gsw = (sg ^ (r & 7)) * 8;
            gload16(A + (size_t)(row0 + r) * K + k0 + gsw, &As[(j * 256 + tid) * 8]);
        }
#pragma unroll
        for (int j = 0; j < 4; j++) {
            int r = j * 32 + sr;
            int gsw = (sg ^ (r & 7)) * 8;
            gload16(Bt + (size_t)(col0 + r) * K + k0 + gsw, &Bs[(j * 256 + tid) * 8]);
        }
        __syncthreads();                       // drains vmcnt -> LDS ready
        bf16x8 af[4][2], bfr[4][2];
#pragma unroll
        for (int i = 0; i < 4; i++) {
            int r = wr + i * 16 + cc;
#pragma unroll
            for (int kk = 0; kk < 2; kk++)
                af[i][kk] = *(const bf16x8*)&As[r * 64 + ((kk * 4 + qg) ^ (r & 7)) * 8];
        }
#pragma unroll
        for (int i = 0; i < 4; i++) {
            int r = wc + i * 16 + cc;
#pragma unroll
            for (int kk = 0; kk < 2; kk++)
                bfr[i][kk] = *(const bf16x8*)&Bs[r * 64 + ((kk * 4 + qg) ^ (r & 7)) * 8];
        }
#pragma unroll
        for (int mi = 0; mi < 4; mi++)
#pragma unroll
            for (int ni = 0; ni < 4; ni++) {
                acc[mi][ni] = __builtin_amdgcn_mfma_f32_16x16x32_bf16(af[mi][0], bfr[ni][0], acc[mi][ni], 0, 0, 0);
                acc[mi][ni] = __builtin_amdgcn_mfma_f32_16x16x32_bf16(af[mi][1], bfr[ni][1], acc[mi][ni], 0, 0, 0);
            }
    }
    // epilogue: D layout col = lane&15, row = (lane>>4)*4 + i
    const int q4 = qg * 4;
    if (EPI == 2) {
#pragma unroll
        for (int mi = 0; mi < 4; mi++) {
            int grow = row0 + wr + mi * 16 + q4;
            int btok = grow >> 11, srem = grow & 2047;   // b constant over i (grow % 4 == 0)
#pragma unroll
            for (int ni = 0; ni < 4; ni++) {
                int gcol = col0 + wc + ni * 16 + cc;
                int sec = gcol >> 9, f = gcol & 511;
                int hh = f >> 6, dd = f & 63;
                if (sec == 0) {
                    float bb = bq[f];
                    size_t base = (((size_t)btok * 8 + hh) * 2048 + srem) * 64 + dd;
#pragma unroll
                    for (int i = 0; i < 4; i++) Qo[base + (size_t)i * 64] = f2bf((acc[mi][ni][i] + bb) * 0.18033688f);
                } else if (sec == 1) {
                    float bb = bk[f];
                    size_t base = (((size_t)btok * 8 + hh) * 2048 + srem) * 64 + dd;
#pragma unroll
                    for (int i = 0; i < 4; i++) Ko[base + (size_t)i * 64] = f2bf(acc[mi][ni][i] + bb);
                } else {
                    float bb = bv[f];
                    size_t base = (((size_t)btok * 8 + hh) * 64 + dd) * 2048 + srem;
#pragma unroll
                    for (int i = 0; i < 4; i++) Vo[base + i] = f2bf(acc[mi][ni][i] + bb);
                }
            }
        }
    } else {
#pragma unroll
        for (int mi = 0; mi < 4; mi++) {
            int grow = row0 + wr + mi * 16 + q4;
#pragma unroll
            for (int ni = 0; ni < 4; ni++) {
                int gcol = col0 + wc + ni * 16 + cc;
                float bb = bias[gcol];
#pragma unroll
                for (int i = 0; i < 4; i++) {
                    float v = acc[mi][ni][i] + bb;
                    if (EPI == 0) Cf[(size_t)(grow + i) * N + gcol] = v;
                    else          Cb[(size_t)(grow + i) * N + gcol] = f2bf(v > 0.f ? v : 0.f);
                }
            }
        }
    }
}

// ---------------- GEMM 64x64 tile, BK=64, double-buffered, fused residual add ----------------
// Cf = A @ Bt^T + bias + Rf  (Rf = residual, read in epilogue under compute shadow).
// grid (N/64, M/64) = 1024 blocks = 4/CU. 4 waves of 32x32.
__global__ __launch_bounds__(256) void gemm64_db(
    const u16* __restrict__ A, const u16* __restrict__ Bt,
    const float* __restrict__ bias, const float* __restrict__ Rf,
    float* __restrict__ Cf, int M, int N, int K)
{
    __shared__ u16 As[2][64 * 64];   // 8KB each, granule ^= row&7
    __shared__ u16 Bs[2][64 * 64];
    const int tid = threadIdx.x;
    const int lane = tid & 63, wid = tid >> 6;
    const int row0 = blockIdx.y * 64, col0 = blockIdx.x * 64;
    const int wr = (wid >> 1) * 32, wc = (wid & 1) * 32;
    const int cc = lane & 15, qg = lane >> 4;
    const int r0 = tid >> 3, g8 = (tid & 7);          // slot tid: row r0, granule g8
    const int gsw0 = (g8 ^ (r0 & 7)) * 8;             // r0 in [0,32)
    const int r1 = r0 + 32;
    const int gsw1 = (g8 ^ (r1 & 7)) * 8;
    f32x4 acc[2][2] = {};
    // prologue: stage k0=0 into buf 0
    gload16(A + (size_t)(row0 + r0) * K + gsw0, &As[0][tid * 8]);
    gload16(A + (size_t)(row0 + r1) * K + gsw1, &As[0][(tid + 256) * 8]);
    gload16(Bt + (size_t)(col0 + r0) * K + gsw0, &Bs[0][tid * 8]);
    gload16(Bt + (size_t)(col0 + r1) * K + gsw1, &Bs[0][(tid + 256) * 8]);
    int cur = 0;
    for (int k0 = 0; k0 < K; k0 += 64) {
        asm volatile("s_waitcnt vmcnt(0)" ::: "memory");
        __syncthreads();                       // cur staged everywhere; prev compute done
        if (k0 + 64 < K) {                     // prefetch next K-tile into other buffer
            int kn = k0 + 64, nb = cur ^ 1;
            gload16(A + (size_t)(row0 + r0) * K + kn + gsw0, &As[nb][tid * 8]);
            gload16(A + (size_t)(row0 + r1) * K + kn + gsw1, &As[nb][(tid + 256) * 8]);
            gload16(Bt + (size_t)(col0 + r0) * K + kn + gsw0, &Bs[nb][tid * 8]);
            gload16(Bt + (size_t)(col0 + r1) * K + kn + gsw1, &Bs[nb][(tid + 256) * 8]);
        }
        bf16x8 af[2][2], bfr[2][2];
#pragma unroll
        for (int i = 0; i < 2; i++) {
            int r = wr + i * 16 + cc;
#pragma unroll
            for (int kk = 0; kk < 2; kk++)
                af[i][kk] = *(const bf16x8*)&As[cur][r * 64 + ((kk * 4 + qg) ^ (r & 7)) * 8];
        }
#pragma unroll
        for (int i = 0; i < 2; i++) {
            int r = wc + i * 16 + cc;
#pragma unroll
            for (int kk = 0; kk < 2; kk++)
                bfr[i][kk] = *(const bf16x8*)&Bs[cur][r * 64 + ((kk * 4 + qg) ^ (r & 7)) * 8];
        }
        __builtin_amdgcn_s_setprio(1);
#pragma unroll
        for (int mi = 0; mi < 2; mi++)
#pragma unroll
            for (int ni = 0; ni < 2; ni++) {
                acc[mi][ni] = __builtin_amdgcn_mfma_f32_16x16x32_bf16(af[mi][0], bfr[ni][0], acc[mi][ni], 0, 0, 0);
                acc[mi][ni] = __builtin_amdgcn_mfma_f32_16x16x32_bf16(af[mi][1], bfr[ni][1], acc[mi][ni], 0, 0, 0);
            }
        __builtin_amdgcn_s_setprio(0);
        cur ^= 1;
    }
    const int q4 = qg * 4;
#pragma unroll
    for (int mi = 0; mi < 2; mi++) {
        int grow = row0 + wr + mi * 16 + q4;
#pragma unroll
        for (int ni = 0; ni < 2; ni++) {
            int gcol = col0 + wc + ni * 16 + cc;
            float bb = bias[gcol];
#pragma unroll
            for (int i = 0; i < 4; i++) {
                size_t idx = (size_t)(grow + i) * N + gcol;
                Cf[idx] = acc[mi][ni][i] + bb + Rf[idx];
            }
        }
    }
}

// ---------------- flash attention v8: fixed-max softmax + permlane P-exchange ----------------
// Qb/Kb: [B][H][S][64] bf16 (q pre-scaled by 0.125*log2e), Vt: [B][H][64][S] bf16
// grid: (bh 32, qt 16); block 256 = 4 waves x 32 q-rows; KV tile 64, double-buffered 32KB LDS.
__global__ __launch_bounds__(256) void flash_attn(
    const u16* __restrict__ Qb, const u16* __restrict__ Kb, const u16* __restrict__ Vt,
    u16* __restrict__ Ob)
{
    __shared__ u16 Ks[2][4096];   // [buf][kv 64][d 64], XOR-swizzled rows
    __shared__ u16 Vs[2][4096];   // [buf][d 64][kv 64], XOR-swizzled rows
    const int tid = threadIdx.x, lane = tid & 63, w = tid >> 6;
    const int l31 = lane & 31, h = lane >> 5;
    const int bh = blockIdx.x, qt = blockIdx.y;
    const u16* Kg = Kb + (size_t)bh * (2048 * 64);
    const u16* Vg = Vt + (size_t)bh * (64 * 2048);

    // Q as MFMA B-operand: lane needs Q[d = f*16 + h*8 + j][q = l31]
    bf16x8 qf[4];
    {
        const u16* Qrow = Qb + ((size_t)bh * 2048 + (size_t)qt * 128 + w * 32 + l31) * 64;
#pragma unroll
        for (int f = 0; f < 4; f++) qf[f] = *(const bf16x8*)(Qrow + f * 16 + h * 8);
    }
    f32x16 os0{}, os1{};
    float lsum = 0.f;

    const int r8 = lane >> 3;                  // row within 8-row chunk
    const int cswz = ((lane & 7) ^ r8) * 8;    // inverse-swizzled source col (u16)
    // prologue: stage tile 0 into buf 0
#pragma unroll
    for (int cc = 0; cc < 2; cc++) {
        int c = w * 2 + cc;
        gload16(Kg + (size_t)(c * 8 + r8) * 64 + cswz, &Ks[0][c * 512]);
        gload16(Vg + (size_t)(c * 8 + r8) * 2048 + cswz, &Vs[0][c * 512]);
    }
    const int swz = (l31 & 7) << 3;            // read-side XOR (u16 units)

    for (int kt = 0; kt < 32; kt++) {
        const int cur = kt & 1;
        asm volatile("s_waitcnt vmcnt(0)" ::: "memory");
        __syncthreads();                        // tile kt staged everywhere; prev compute done
        if (kt < 31) {                          // prefetch kt+1 into other buffer
#pragma unroll
            for (int cc = 0; cc < 2; cc++) {
                int c = w * 2 + cc;
                gload16(Kg + (size_t)(kt + 1) * 4096 + (size_t)(c * 8 + r8) * 64 + cswz, &Ks[cur ^ 1][c * 512]);
                gload16(Vg + (size_t)(c * 8 + r8) * 2048 + (size_t)(kt + 1) * 64 + cswz, &Vs[cur ^ 1][c * 512]);
            }
        }
        // ---- swapped QK^T: P^T[key][q], lane: q=l31, key=(r&3)+8*(r>>2)+4*h (+32 for p1) ----
        f32x16 p0{}, p1{};
        {
            const u16* kb = &Ks[cur][0];
            __builtin_amdgcn_s_setprio(1);
#pragma unroll
            for (int f = 0; f < 4; f++) {
                int colu = (f * 16 + h * 8) ^ swz;
                bf16x8 ka0 = *(const bf16x8*)(kb + l31 * 64 + colu);
                bf16x8 ka1 = *(const bf16x8*)(kb + (32 + l31) * 64 + colu);
                p0 = __builtin_amdgcn_mfma_f32_32x32x16_bf16(ka0, qf[f], p0, 0, 0, 0);
                p1 = __builtin_amdgcn_mfma_f32_32x32x16_bf16(ka1, qf[f], p1, 0, 0, 0);
            }
            __builtin_amdgcn_s_setprio(0);
        }
        // ---- fixed-max softmax: P = exp2(score) directly, per-lane partial sum ----
        float ss[4] = {};
#pragma unroll
        for (int r = 0; r < 16; r++) { float e = __builtin_amdgcn_exp2f(p0[r]); p0[r] = e; ss[r & 3] += e; }
#pragma unroll
        for (int r = 0; r < 16; r++) { float e = __builtin_amdgcn_exp2f(p1[r]); p1[r] = e; ss[r & 3] += e; }
        lsum += (ss[0] + ss[1]) + (ss[2] + ss[3]);
        // ---- pack P to bf16 pairs, permlane32_swap cross-half exchange (VALU, no LDS), PV ----
        const u16* vb = &Vs[cur][0];
#pragma unroll
        for (int t = 0; t < 2; t++) {
            u32 pk[8];
#pragma unroll
            for (int j = 0; j < 8; j++) {
                float a = t ? p1[2 * j] : p0[2 * j];
                float b = t ? p1[2 * j + 1] : p0[2 * j + 1];
                pk[j] = (u32)bfu(a) | ((u32)bfu(b) << 16);
            }
            u32 x0 = pk[0], y0 = pk[2]; pl32swap(x0, y0);
            u32 x1 = pk[1], y1 = pk[3]; pl32swap(x1, y1);
            u32 x2 = pk[4], y2 = pk[6]; pl32swap(x2, y2);
            u32 x3 = pk[5], y3 = pk[7]; pl32swap(x3, y3);
            union { u32 u[4]; bf16x8 v; } fA, fB;
            fA.u[0] = x0; fA.u[1] = x1; fA.u[2] = y0; fA.u[3] = y1;
            fB.u[0] = x2; fB.u[1] = x3; fB.u[2] = y2; fB.u[3] = y3;
            __builtin_amdgcn_s_setprio(1);
#pragma unroll
            for (int f = 0; f < 2; f++) {
                bf16x8 pa = f ? fB.v : fA.v;
                int colu = (t * 32 + f * 16 + h * 8) ^ swz;
                bf16x8 v0 = *(const bf16x8*)(vb + l31 * 64 + colu);
                bf16x8 v1 = *(const bf16x8*)(vb + (32 + l31) * 64 + colu);
                os0 = __builtin_amdgcn_mfma_f32_32x32x16_bf16(pa, v0, os0, 0, 0, 0);
                os1 = __builtin_amdgcn_mfma_f32_32x32x16_bf16(pa, v1, os1, 0, 0, 0);
            }
            __builtin_amdgcn_s_setprio(0);
        }
    }
    // ---- epilogue: one cross-half reduce of l, then O = os / l ----
    lsum += __shfl_xor(lsum, 32);
    float rl = 1.f / lsum;
    const int hatt = bh & 7, b_ = bh >> 3;
#pragma unroll
    for (int r = 0; r < 16; r++) {
        int qrow = (r & 3) + 8 * (r >> 2) + 4 * h;
        float rlq = __shfl(rl, qrow);
        int tok = qt * 128 + w * 32 + qrow;
        u16* po = Ob + ((size_t)b_ * 2048 + tok) * 512 + hatt * 64;
        po[l31] = bfu(os0[r] * rlq);
        po[32 + l31] = bfu(os1[r] * rlq);
    }
}

// ---------------- single-input LayerNorm (residual pre-added in GEMM epilogue) --------------
__global__ __launch_bounds__(256) void ln_one(
    const float* __restrict__ Y,
    const float* __restrict__ g, const float* __restrict__ bta,
    float* __restrict__ Of, u16* __restrict__ Ob)
{
    const int lane = threadIdx.x & 63;
    const int row = blockIdx.x * 4 + (threadIdx.x >> 6);
    const size_t base = (size_t)row * 512 + lane * 8;
    float4 y0 = *(const float4*)(Y + base);
    float4 y1 = *(const float4*)(Y + base + 4);
    float t[8] = {y0.x, y0.y, y0.z, y0.w, y1.x, y1.y, y1.z, y1.w};
    float s = 0.f, s2 = 0.f;
#pragma unroll
    for (int j = 0; j < 8; j++) { s += t[j]; s2 += t[j] * t[j]; }
#pragma unroll
    for (int off = 1; off < 64; off <<= 1) { s += __shfl_xor(s, off); s2 += __shfl_xor(s2, off); }
    float mean = s * (1.f / 512.f);
    float var = s2 * (1.f / 512.f) - mean * mean;
    float rs = rsqrtf(var + 1e-5f);
    float4 g0 = *(const float4*)(g + lane * 8);
    float4 g1 = *(const float4*)(g + lane * 8 + 4);
    float4 b0 = *(const float4*)(bta + lane * 8);
    float4 b1 = *(const float4*)(bta + lane * 8 + 4);
    float gg[8] = {g0.x, g0.y, g0.z, g0.w, g1.x, g1.y, g1.z, g1.w};
    float bb[8] = {b0.x, b0.y, b0.z, b0.w, b1.x, b1.y, b1.z, b1.w};
    float o[8];
#pragma unroll
    for (int j = 0; j < 8; j++) o[j] = (t[j] - mean) * rs * gg[j] + bb[j];
    *(float4*)(Of + base) = make_float4(o[0], o[1], o[2], o[3]);
    *(float4*)(Of + base + 4) = make_float4(o[4], o[5], o[6], o[7]);
    u32 p0 = (u32)f2bf(o[0]) | ((u32)f2bf(o[1]) << 16);
    u32 p1 = (u32)f2bf(o[2]) | ((u32)f2bf(o[3]) << 16);
    u32 p2 = (u32)f2bf(o[4]) | ((u32)f2bf(o[5]) << 16);
    u32 p3 = (u32)f2bf(o[6]) | ((u32)f2bf(o[7]) << 16);
    *(uint4*)(Ob + base) = make_uint4(p0, p1, p2, p3);
}

// ---------------- output projection: out = x @ W_out + b_out (N=20, fp32), ILP 4 ----------------
__global__ __launch_bounds__(320) void out_proj(const float* __restrict__ x,
    const float* __restrict__ W, const float* __restrict__ b, float* __restrict__ out)
{
    int t = blockIdx.x * 320 + threadIdx.x;
    int m = t / 20, o = t - m * 20;
    const float* xr = x + (size_t)m * 512;
    float a0 = b[o], a1 = 0.f, a2 = 0.f, a3 = 0.f;
#pragma unroll 4
    for (int k = 0; k < 512; k += 4) {
        a0 = fmaf(xr[k],     W[k * 20 + o],       a0);
        a1 = fmaf(xr[k + 1], W[(k + 1) * 20 + o], a1);
        a2 = fmaf(xr[k + 2], W[(k + 2) * 20 + o], a2);
        a3 = fmaf(xr[k + 3], W[(k + 3) * 20 + o], a3);
    }
    out[(size_t)m * 20 + o] = (a0 + a1) + (a2 + a3);
}

extern "C" void kernel_launch(void* const* d_in, const int* in_sizes, int n_in,
                              void* d_out, int out_size, void* d_ws, size_t ws_size,
                              hipStream_t stream)
{
    const float* src  = (const float*)d_in[0];
    const float* W_in = (const float*)d_in[1];
    const float* b_in = (const float*)d_in[2];
    const float* Wq   = (const float*)d_in[3];
    const float* bq   = (const float*)d_in[4];
    const float* Wk   = (const float*)d_in[5];
    const float* bk   = (const float*)d_in[6];
    const float* Wv   = (const float*)d_in[7];
    const float* bv   = (const float*)d_in[8];
    const float* Wo   = (const float*)d_in[9];
    const float* bo   = (const float*)d_in[10];
    const float* ln1g = (const float*)d_in[11];
    const float* ln1b = (const float*)d_in[12];
    const float* W1   = (const float*)d_in[13];
    const float* b1   = (const float*)d_in[14];
    const float* W2   = (const float*)d_in[15];
    const float* b2   = (const float*)d_in[16];
    const float* ln2g = (const float*)d_in[17];
    const float* ln2b = (const float*)d_in[18];
    const float* Wout = (const float*)d_in[19];
    const float* bout = (const float*)d_in[20];

    char* ws = (char*)d_ws;
    size_t off = 0;
    auto take = [&](size_t bytes) -> void* {
        off = (off + 255) & ~(size_t)255;
        void* p = ws + off;
        off += bytes;
        return p;
    };
    const size_t TOK = 8192, D = 512;
    u16*   qkvt = (u16*)take(6ull * 1536 * 512 * 2);
    u16*   wot  = (u16*)take(6ull * 512 * 512 * 2);
    u16*   w1t  = (u16*)take(6ull * 2048 * 512 * 2);
    u16*   w2t  = (u16*)take(6ull * 512 * 2048 * 2);
    float* xf   = (float*)take(TOK * D * 4);
    u16*   xb   = (u16*)take(TOK * D * 2);
    u16*   sh4  = (u16*)take(4ull * TOK * D * 2);   // qb|kb|vtb|ob, reused as ff
    float* scr  = (float*)take(TOK * D * 4);        // (attn|ff2) + bias + residual, f32
    float* h1f  = (float*)take(TOK * D * 4);
    u16*   h1b  = (u16*)take(TOK * D * 2);
    if (off > ws_size) return;   // workspace too small -> fail cleanly

    u16* qb  = sh4;
    u16* kb_ = sh4 + TOK * D;
    u16* vtb = sh4 + 2 * TOK * D;
    u16* ob  = sh4 + 3 * TOK * D;
    u16* ffb = sh4;              // [8192][2048] bf16, alias of q/k/v/o region

    dim3 tb(32, 8);
    wtrans<<<dim3(16, 16, 6), tb, 0, stream>>>(Wq, qkvt, 512, 512, 0,    512, 1536ll * 512);
    wtrans<<<dim3(16, 16, 6), tb, 0, stream>>>(Wk, qkvt, 512, 512, 512,  512, 1536ll * 512);
    wtrans<<<dim3(16, 16, 6), tb, 0, stream>>>(Wv, qkvt, 512, 512, 1024, 512, 1536ll * 512);
    wtrans<<<dim3(16, 16, 6), tb, 0, stream>>>(Wo, wot,  512, 512, 0,    512, 512ll * 512);
    wtrans<<<dim3(64, 16, 6), tb, 0, stream>>>(W1, w1t,  512, 2048, 0,   512, 2048ll * 512);
    wtrans<<<dim3(16, 64, 6), tb, 0, stream>>>(W2, w2t,  2048, 512, 0,  2048, 512ll * 2048);

    input_proj<<<16384, 256, 0, stream>>>(src, W_in, b_in, xf, xb);

    for (int l = 0; l < 6; l++) {
        const u16* qkvt_l = qkvt + (size_t)l * 1536 * 512;
        const u16* wot_l  = wot  + (size_t)l * 512 * 512;
        const u16* w1t_l  = w1t  + (size_t)l * 2048 * 512;
        const u16* w2t_l  = w2t  + (size_t)l * 512 * 2048;

        gemm_bt<2><<<dim3(12, 64), 256, 0, stream>>>(xb, qkvt_l, nullptr,
            nullptr, nullptr, qb, kb_, vtb,
            bq + l * 512, bk + l * 512, bv + l * 512, 8192, 1536, 512);

        flash_attn<<<dim3(32, 16), 256, 0, stream>>>(qb, kb_, vtb, ob);

        // scr = attn @ Wo + bo + x   (residual fused into epilogue)
        gemm64_db<<<dim3(8, 128), 256, 0, stream>>>(ob, wot_l, bo + l * 512,
            xf, scr, 8192, 512, 512);

        ln_one<<<2048, 256, 0, stream>>>(scr, ln1g + l * 512, ln1b + l * 512, h1f, h1b);

        gemm_bt<1><<<dim3(16, 64), 256, 0, stream>>>(h1b, w1t_l, b1 + l * 2048,
            nullptr, ffb, nullptr, nullptr, nullptr, nullptr, nullptr, nullptr,
            8192, 2048, 512);

        // scr = ff @ W2 + b2 + h   (residual fused into epilogue)
        gemm64_db<<<dim3(8, 128), 256, 0, stream>>>(ffb, w2t_l, b2 + l * 512,
            h1f, scr, 8192, 512, 2048);

        ln_one<<<2048, 256, 0, stream>>>(scr, ln2g + l * 512, ln2b + l * 512, xf, xb);
    }

    out_proj<<<512, 320, 0, stream>>>(xf, Wout, bout, (float*)d_out);
}